// Round 10
// baseline (1711.586 us; speedup 1.0000x reference)
//
#include <hip/hip_runtime.h>
#include <cstddef>
#include <math.h>

// Problem constants (from reference)
#define BATCH 128
#define DIN   2048
#define NN    2048
#define TT    50
#define MM    (BATCH * TT)   // 6400, m = b*50 + t
#define BN_EPS 1e-4
#define NDIG  5

typedef double double4_t __attribute__((ext_vector_type(4)));
typedef int    int4v    __attribute__((ext_vector_type(4)));

#define SWZ(x) (((x) & 7) << 2)

// ===========================================================================
// TIER 1: exact int8-Ozaki GEMM (validated round 9: spike-exact, absmax OK).
// 5 signed 7-bit digits vs per-row 2^e scale; 15 digit-pair GEMMs (i+j<=4) in
// exact int32 MFMA; fp64 recombine. i8 MFMA layouts HW-verified (round-8
// probe, code 1 = standard): A m=lane&15, k=(lane>>4)*16+byte; B symmetric;
// D row=4*(lane>>4)+reg, col=lane&15.
// Round-10 changes: parallel splits (was ~0.5 block/CU), LLC panel swizzle in
// the GEMM (FETCH was 1.38 GB for 86 MB of inputs), register prefetch.
// ===========================================================================

// --- zero the (b,t) max buffer --------------------------------------------
__global__ __launch_bounds__(256) void a_init_kernel(int* maxbuf) {
    const int idx = blockIdx.x * 256 + threadIdx.x;
    if (idx < MM) maxbuf[idx] = 0;
}

// --- per-(b,t) absmax over k, 1024 blocks; X >= 0 so int-cmp == float-cmp --
__global__ __launch_bounds__(256) void a_max_kernel(
    const float* __restrict__ X, int* __restrict__ maxbuf)
{
    __shared__ float red[4][64];
    const int b  = blockIdx.x;
    const int k0 = blockIdx.y * 256;
    const int tid = threadIdx.x;
    const int tl = tid & 63;          // t lane (valid < 50)
    const int kg = tid >> 6;          // 0..3
    const float* Xb = X + (size_t)b * (DIN * TT);

    float m_loc = 0.f;
    if (tl < TT) {
        const float* p = Xb + (size_t)(k0 + kg * 64) * TT + tl;
#pragma unroll 8
        for (int i = 0; i < 64; ++i)
            m_loc = fmaxf(m_loc, fabsf(p[i * TT]));
    }
    red[kg][tl] = m_loc;
    __syncthreads();
    if (kg == 0 && tl < TT) {
        float m = fmaxf(fmaxf(red[0][tl], red[1][tl]),
                        fmaxf(red[2][tl], red[3][tl]));
        atomicMax(&maxbuf[b * TT + tl], __float_as_int(m));
    }
}

// --- maxbuf -> sA (float, 2^(6-e)) and invA (double, 2^(e-6)) --------------
__global__ __launch_bounds__(256) void a_scale_kernel(
    const int* __restrict__ maxbuf, float* __restrict__ sAf,
    double* __restrict__ invA)
{
    const int idx = blockIdx.x * 256 + threadIdx.x;
    if (idx >= MM) return;
    float m = __int_as_float(maxbuf[idx]);
    if (m == 0.f) m = 1.f;
    int ex; frexpf(m, &ex);
    sAf[idx]  = exp2f((float)(6 - ex));
    invA[idx] = ldexp(1.0, ex - 6);
}

// --- digit split A with LDS transpose; grid (128 b, 8 kc) ------------------
__global__ __launch_bounds__(256) void a_split_kernel(
    const float* __restrict__ X, const float* __restrict__ sAf,
    signed char* __restrict__ Adig)
{
    __shared__ float Xs[256 * 51];    // [k_local][t], pad 51 -> conflict-free
    __shared__ float sAs[TT];

    const int b  = blockIdx.x;
    const int k0 = blockIdx.y * 256;
    const int tid = threadIdx.x;
    const float* Xb = X + (size_t)b * (DIN * TT) + (size_t)k0 * TT;

    for (int idx = tid; idx < 256 * TT; idx += 256) {
        const int kl = idx / TT, t = idx - kl * TT;
        Xs[kl * 51 + t] = Xb[idx];    // flat-coalesced source
    }
    if (tid < TT) sAs[tid] = sAf[b * TT + tid];
    __syncthreads();

    // thread = k_local; loop t. Writes: lanes -> consecutive k bytes.
    const size_t kcol = (size_t)(k0 + tid);
    for (int t = 0; t < TT; ++t) {
        float r = Xs[tid * 51 + t] * sAs[t];
        const size_t mrow = (size_t)b * TT + t;
#pragma unroll
        for (int i = 0; i < NDIG; ++i) {
            float di = rintf(r);
            r = (r - di) * 128.f;     // exact in fp32
            Adig[((size_t)i * MM + mrow) * DIN + kcol] = (signed char)(int)di;
        }
    }
}

// --- split B: one block per n ----------------------------------------------
__global__ __launch_bounds__(256) void b_split_kernel(
    const float* __restrict__ W, signed char* __restrict__ Bdig,
    double* __restrict__ invB)
{
    __shared__ float red[256];
    __shared__ float sBsh;
    const int n = blockIdx.x;
    const int tid = threadIdx.x;
    const float* Wr = W + (size_t)n * DIN;

    float m_loc = 0.f;
#pragma unroll
    for (int i = 0; i < 8; ++i)
        m_loc = fmaxf(m_loc, fabsf(Wr[tid + 256 * i]));
    red[tid] = m_loc;
    __syncthreads();
    for (int s = 128; s > 0; s >>= 1) {
        if (tid < s) red[tid] = fmaxf(red[tid], red[tid + s]);
        __syncthreads();
    }
    if (tid == 0) {
        float m = (red[0] == 0.f) ? 1.f : red[0];
        int ex; frexpf(m, &ex);
        sBsh = exp2f((float)(6 - ex));
        invB[n] = ldexp(1.0, ex - 6);
    }
    __syncthreads();
    const float sB = sBsh;
#pragma unroll
    for (int i = 0; i < 8; ++i) {
        const int k = tid + 256 * i;
        float r = Wr[k] * sB;
#pragma unroll
        for (int d = 0; d < NDIG; ++d) {
            float di = rintf(r);
            r = (r - di) * 128.f;
            Bdig[((size_t)d * NN + n) * DIN + k] = (signed char)(int)di;
        }
    }
}

// --- i8 GEMM: 64x64 tile, LLC panel swizzle, register prefetch -------------
__global__ __launch_bounds__(256, 4) void gemm_i8_kernel(
    const signed char* __restrict__ Adig,   // [5][MM][DIN]
    const signed char* __restrict__ Bdig,   // [5][NN][DIN]
    const double* __restrict__ invA,        // [MM]
    const double* __restrict__ invB,        // [NN]
    double* __restrict__ PSP)               // [MM][NN]
{
    __shared__ __align__(16) signed char Asd[NDIG][64][64];
    __shared__ __align__(16) signed char Bsd[NDIG][64][64];

    const int tid = threadIdx.x;
    // panel swizzle: 4 panels x (25 m-blocks x 32 n-blocks), n fastest:
    // A strip L2-resident across 32 consecutive blocks; B LLC-resident.
    const int bx     = blockIdx.x;          // 0..3199
    const int panel  = bx / 800;
    const int within = bx - panel * 800;
    const int m0 = (panel * 25 + within / 32) * 64;
    const int n0 = (within & 31) * 64;

    const int s_row = tid >> 2;
    const int s_k   = (tid & 3) * 16;

    const int lane = tid & 63;
    const int wv   = tid >> 6;
    const int wm   = (wv >> 1) * 32;
    const int wn   = (wv & 1) * 32;
    const int row  = lane & 15;
    const int grp  = lane >> 4;

    const signed char* Ag = Adig + ((size_t)m0 + s_row) * DIN + s_k;  // + p*MM*DIN + k0
    const signed char* Bg = Bdig + ((size_t)n0 + s_row) * DIN + s_k;

    int4v acc[NDIG][2][2];
#pragma unroll
    for (int w = 0; w < NDIG; ++w)
#pragma unroll
        for (int i = 0; i < 2; ++i)
#pragma unroll
            for (int j = 0; j < 2; ++j) acc[w][i][j] = int4v{0, 0, 0, 0};

    // prologue: stage k-tile 0
#pragma unroll
    for (int p = 0; p < NDIG; ++p) {
        *(int4*)&Asd[p][s_row][s_k] = *(const int4*)(Ag + (size_t)p * MM * DIN);
        *(int4*)&Bsd[p][s_row][s_k] = *(const int4*)(Bg + (size_t)p * NN * DIN);
    }

    for (int it = 0; it < DIN / 64; ++it) {
        __syncthreads();   // tile `it` visible

        int4 ga[NDIG], gb[NDIG];
        if (it + 1 < DIN / 64) {
            const int k0n = (it + 1) * 64;
#pragma unroll
            for (int p = 0; p < NDIG; ++p) {
                ga[p] = *(const int4*)(Ag + (size_t)p * MM * DIN + k0n);
                gb[p] = *(const int4*)(Bg + (size_t)p * NN * DIN + k0n);
            }
        }

        int4v aF[NDIG][2];
#pragma unroll
        for (int i = 0; i < NDIG; ++i) {
            aF[i][0] = *(const int4v*)&Asd[i][wm + row][grp * 16];
            aF[i][1] = *(const int4v*)&Asd[i][wm + row + 16][grp * 16];
        }
#pragma unroll
        for (int j = 0; j < NDIG; ++j) {
            const int4v bF0 = *(const int4v*)&Bsd[j][wn + row][grp * 16];
            const int4v bF1 = *(const int4v*)&Bsd[j][wn + row + 16][grp * 16];
#pragma unroll
            for (int i = 0; i + j < NDIG; ++i) {
                const int w = i + j;
                acc[w][0][0] = __builtin_amdgcn_mfma_i32_16x16x64_i8(aF[i][0], bF0, acc[w][0][0], 0, 0, 0);
                acc[w][0][1] = __builtin_amdgcn_mfma_i32_16x16x64_i8(aF[i][0], bF1, acc[w][0][1], 0, 0, 0);
                acc[w][1][0] = __builtin_amdgcn_mfma_i32_16x16x64_i8(aF[i][1], bF0, acc[w][1][0], 0, 0, 0);
                acc[w][1][1] = __builtin_amdgcn_mfma_i32_16x16x64_i8(aF[i][1], bF1, acc[w][1][1], 0, 0, 0);
            }
        }

        __syncthreads();   // frag reads of tile `it` complete

        if (it + 1 < DIN / 64) {
#pragma unroll
            for (int p = 0; p < NDIG; ++p) {
                *(int4*)&Asd[p][s_row][s_k] = ga[p];
                *(int4*)&Bsd[p][s_row][s_k] = gb[p];
            }
        }
    }

    const double c1 = 1.0 / 128.0, c2 = c1 * c1, c3 = c2 * c1, c4 = c2 * c2;
#pragma unroll
    for (int ih = 0; ih < 2; ++ih)
#pragma unroll
        for (int jh = 0; jh < 2; ++jh) {
            const int ncol = n0 + wn + 16 * jh + row;
            const double ib = invB[ncol];
#pragma unroll
            for (int r = 0; r < 4; ++r) {
                const int mrow = m0 + wm + 16 * ih + 4 * grp + r;
                double s = (double)acc[0][ih][jh][r]
                         + c1 * (double)acc[1][ih][jh][r]
                         + c2 * (double)acc[2][ih][jh][r]
                         + c3 * (double)acc[3][ih][jh][r]
                         + c4 * (double)acc[4][ih][jh][r];
                PSP[(size_t)mrow * NN + ncol] = s * invA[mrow] * ib;
            }
        }
}

// ===========================================================================
// TIER 2 fallback: fp64-MFMA GEMM (round-8, proven)
// ===========================================================================
#define BKK 32

template <typename PT>
__global__ __launch_bounds__(256, 5) void gemm_psp_kernel(
    const float* __restrict__ X, const float* __restrict__ W,
    PT* __restrict__ PSP)
{
    __shared__ float As[2][BKK][64];
    __shared__ float Bs[2][64][BKK];

    const int tid = threadIdx.x;
    const int m0 = blockIdx.y * 64;
    const int n0 = blockIdx.x * 64;

    const int a_m = tid & 63;
    const int a_k = tid >> 6;
    const int m_g = m0 + a_m;
    const int ab  = m_g / TT;
    const int at  = m_g - ab * TT;
    const float* Aptr = X + (size_t)ab * (DIN * TT) + at;

    const int b_n = tid >> 2;
    const int b_k = (tid & 3) * 8;
    const float* Wptr = W + (size_t)(n0 + b_n) * DIN + b_k;
    const int bswz_st = SWZ(b_n);

    const int lane = tid & 63;
    const int wv   = tid >> 6;
    const int wm   = (wv >> 1) * 32;
    const int wn   = (wv & 1) * 32;
    const int row  = lane & 15;
    const int grp  = lane >> 4;
    const int bswz_rd = SWZ(row);

    double4_t acc[2][2];
#pragma unroll
    for (int i = 0; i < 2; ++i)
#pragma unroll
        for (int j = 0; j < 2; ++j) acc[i][j] = double4_t{0.0, 0.0, 0.0, 0.0};

    {
#pragma unroll
        for (int j = 0; j < 8; ++j) {
            const int kr = a_k + 4 * j;
            As[0][kr][a_m ^ SWZ(kr)] = Aptr[kr * TT];
        }
        *(float4*)&Bs[0][b_n][(b_k + 0) ^ bswz_st] = *(const float4*)(Wptr);
        *(float4*)&Bs[0][b_n][(b_k + 4) ^ bswz_st] = *(const float4*)(Wptr + 4);
    }

    const int NIT = DIN / BKK;
    for (int it = 0; it < NIT; ++it) {
        const int buf = it & 1;
        __syncthreads();

        float a_nxt[8];
        float4 b_nxt0, b_nxt1;
        if (it + 1 < NIT) {
            const int k0n = (it + 1) * BKK;
#pragma unroll
            for (int j = 0; j < 8; ++j)
                a_nxt[j] = Aptr[(k0n + a_k + 4 * j) * TT];
            b_nxt0 = *(const float4*)(Wptr + k0n);
            b_nxt1 = *(const float4*)(Wptr + k0n + 4);
        }

#pragma unroll
        for (int kq = 0; kq < BKK; kq += 4) {
            const int kr = kq + grp;
            const int aswz = SWZ(kr);
            const double a0 = (double)As[buf][kr][(wm + row) ^ aswz];
            const double a1 = (double)As[buf][kr][(wm + row + 16) ^ aswz];
            const double b0 = (double)Bs[buf][wn + row][kr ^ bswz_rd];
            const double b1 = (double)Bs[buf][wn + row + 16][kr ^ bswz_rd];
            acc[0][0] = __builtin_amdgcn_mfma_f64_16x16x4f64(a0, b0, acc[0][0], 0, 0, 0);
            acc[0][1] = __builtin_amdgcn_mfma_f64_16x16x4f64(a0, b1, acc[0][1], 0, 0, 0);
            acc[1][0] = __builtin_amdgcn_mfma_f64_16x16x4f64(a1, b0, acc[1][0], 0, 0, 0);
            acc[1][1] = __builtin_amdgcn_mfma_f64_16x16x4f64(a1, b1, acc[1][1], 0, 0, 0);
        }

        if (it + 1 < NIT) {
            const int nb = 1 - buf;
#pragma unroll
            for (int j = 0; j < 8; ++j) {
                const int kr = a_k + 4 * j;
                As[nb][kr][a_m ^ SWZ(kr)] = a_nxt[j];
            }
            *(float4*)&Bs[nb][b_n][(b_k + 0) ^ bswz_st] = b_nxt0;
            *(float4*)&Bs[nb][b_n][(b_k + 4) ^ bswz_st] = b_nxt1;
        }
    }

#pragma unroll
    for (int i = 0; i < 2; ++i)
#pragma unroll
        for (int j = 0; j < 2; ++j)
#pragma unroll
            for (int r = 0; r < 4; ++r) {
                const int mrow = m0 + wm + 16 * i + grp + 4 * r;   // f64 H2 layout
                PSP[(size_t)mrow * NN + (n0 + wn + 16 * j + row)] = (PT)acc[i][j][r];
            }
}

// ---------------------------------------------------------------------------
// BN stats + LIF recurrence (shared)
// ---------------------------------------------------------------------------
template <typename PT>
__global__ __launch_bounds__(256) void stats_kernel(
    const PT* __restrict__ PSP, const float* __restrict__ bias,
    double* __restrict__ mean_out, double* __restrict__ invstd_out)
{
    const int t = blockIdx.x >> 3;
    const int n = ((blockIdx.x & 7) << 8) + threadIdx.x;
    const double bb = (double)bias[n];
    const PT* p = PSP + (size_t)t * NN + n;

    double s = 0.0;
#pragma unroll 8
    for (int b = 0; b < BATCH; ++b) s += (double)p[(size_t)b * (TT * NN)];
    const double mean = s * (1.0 / BATCH) + bb;

    double ss = 0.0;
#pragma unroll 8
    for (int b = 0; b < BATCH; ++b) {
        double d = ((double)p[(size_t)b * (TT * NN)] + bb) - mean;
        ss += d * d;
    }
    mean_out[t * NN + n]   = mean;
    invstd_out[t * NN + n] = 1.0 / sqrt(ss * (1.0 / BATCH) + BN_EPS);
}

template <typename PT>
__global__ __launch_bounds__(256) void recur_kernel(
    const PT* __restrict__ PSP, const float* __restrict__ bias,
    const double* __restrict__ mean_arr, const double* __restrict__ invstd_arr,
    const float* __restrict__ gamma, const float* __restrict__ decay_v,
    const float* __restrict__ reset_decay, const float* __restrict__ reset_v,
    float* __restrict__ out)
{
    __shared__ float spk[256 * (TT + 1)];

    const int b  = blockIdx.x >> 3;
    const int nc = blockIdx.x & 7;
    const int n  = (nc << 8) + threadIdx.x;
    const int tid = threadIdx.x;

    const double dv = (double)decay_v[n];
    const double rd = (double)reset_decay[n];
    const double rv = (double)reset_v[n];
    const double bb = (double)bias[n];

    double v = 0.0, r = 0.0;
    const PT* p = PSP + (size_t)b * (TT * NN) + n;
    const float* ga = gamma + n;
    const double* me = mean_arr + n;
    const double* is = invstd_arr + n;

    for (int t = 0; t < TT; ++t) {
        const double psp = (double)p[t * NN] + bb;
        const double bn  = (double)ga[t * NN] * (psp - me[t * NN]) * is[t * NN];
        v = v * dv + bn - r;
        const double s = (v > 1.0) ? 1.0 : 0.0;
        r = r * rd + s * rv;
        spk[tid * (TT + 1) + t] = (float)s;
    }
    __syncthreads();

    const size_t base = (size_t)b * (NN * TT) + (size_t)nc * (256 * TT);
    for (int i = tid; i < 256 * TT; i += 256) {
        const int n_l = i / TT;
        out[base + i] = spk[n_l * (TT + 1) + (i - n_l * TT)];
    }

    const size_t fin = (size_t)BATCH * NN * TT;
    out[fin + (size_t)b * NN + n]                      = (float)v;
    out[fin + (size_t)BATCH * NN + (size_t)b * NN + n] = (float)r;
}

// ---------------------------------------------------------------------------
template <typename PT>
static void launch_fp64(const float* X, const float* W, const float* bias,
                        const float* gamma, const float* decay_v,
                        const float* reset_dec, const float* reset_v,
                        float* out, void* d_ws, hipStream_t stream)
{
    PT* PSP = (PT*)d_ws;
    char* after = (char*)d_ws + (size_t)MM * NN * sizeof(PT);
    double* meanA  = (double*)after;
    double* invstd = meanA + (size_t)TT * NN;

    dim3 ggrid(NN / 64, MM / 64);
    gemm_psp_kernel<PT><<<ggrid, 256, 0, stream>>>(X, W, PSP);
    stats_kernel<PT><<<TT * (NN / 256), 256, 0, stream>>>(PSP, bias, meanA, invstd);
    recur_kernel<PT><<<BATCH * (NN / 256), 256, 0, stream>>>(
        PSP, bias, meanA, invstd, gamma, decay_v, reset_dec, reset_v, out);
}

extern "C" void kernel_launch(void* const* d_in, const int* in_sizes, int n_in,
                              void* d_out, int out_size, void* d_ws, size_t ws_size,
                              hipStream_t stream) {
    (void)in_sizes; (void)n_in; (void)out_size;
    const float* X          = (const float*)d_in[0];
    const float* W          = (const float*)d_in[1];
    const float* bias       = (const float*)d_in[2];
    const float* gamma      = (const float*)d_in[3];
    const float* decay_v    = (const float*)d_in[4];
    const float* reset_dec  = (const float*)d_in[5];
    const float* reset_v    = (const float*)d_in[6];
    float* out = (float*)d_out;

    const size_t psp_d   = (size_t)MM * NN * sizeof(double);   // 104.86 MB
    const size_t stats_b = (size_t)TT * NN * 2 * sizeof(double);
    const size_t adig_b  = (size_t)NDIG * MM * DIN;            // 65.54 MB
    const size_t bdig_b  = (size_t)NDIG * NN * DIN;            // 20.97 MB
    const size_t need_i8 = psp_d + stats_b + adig_b + bdig_b + (MM + NN) * sizeof(double);
    const size_t need_d  = psp_d + stats_b;

    if (ws_size >= need_i8) {
        double* PSP    = (double*)d_ws;
        char*   cur    = (char*)d_ws + psp_d;
        double* meanA  = (double*)cur;              cur += (size_t)TT * NN * 8;
        double* invstd = (double*)cur;              cur += (size_t)TT * NN * 8;
        signed char* Adig = (signed char*)cur;      cur += adig_b;
        signed char* Bdig = (signed char*)cur;      cur += bdig_b;
        double* invA   = (double*)cur;              cur += (size_t)MM * 8;
        double* invB   = (double*)cur;
        // transient scratch inside the (not-yet-written) PSP region:
        int*   maxbuf  = (int*)d_ws;                // MM ints
        float* sAf     = (float*)d_ws + MM;         // MM floats

        a_init_kernel<<<(MM + 255) / 256, 256, 0, stream>>>(maxbuf);
        a_max_kernel<<<dim3(BATCH, DIN / 256), 256, 0, stream>>>(X, maxbuf);
        a_scale_kernel<<<(MM + 255) / 256, 256, 0, stream>>>(maxbuf, sAf, invA);
        a_split_kernel<<<dim3(BATCH, DIN / 256), 256, 0, stream>>>(X, sAf, Adig);
        b_split_kernel<<<NN, 256, 0, stream>>>(W, Bdig, invB);
        gemm_i8_kernel<<<(MM / 64) * (NN / 64), 256, 0, stream>>>(
            Adig, Bdig, invA, invB, PSP);
        stats_kernel<double><<<TT * (NN / 256), 256, 0, stream>>>(PSP, bias, meanA, invstd);
        recur_kernel<double><<<BATCH * (NN / 256), 256, 0, stream>>>(
            PSP, bias, meanA, invstd, gamma, decay_v, reset_dec, reset_v, out);
    } else if (ws_size >= need_d) {
        launch_fp64<double>(X, W, bias, gamma, decay_v, reset_dec, reset_v, out, d_ws, stream);
    } else {
        launch_fp64<float>(X, W, bias, gamma, decay_v, reset_dec, reset_v, out, d_ws, stream);
    }
}